// Round 7
// baseline (26.993 us; speedup 1.0000x reference)
//
#include <hip/hip_runtime.h>

// EmbeddingBag(mean): B=1024, S=256, W=16, EMB=50, vocab=256.
// Round 7: r6 pipeline + in-block DESCENDING length sort.
//  - Divergence model: per-row if(len>k) skips at wave granularity; a wave
//    holds ~5 bags, E[max len]~13.3 vs E[len]=8.5. Sorting the block's 512
//    bags by length makes waves length-uniform -> ~8.7 rows/wave on the DS
//    pipe (the largest cost term).
//  - r5's sort failed from lost prefetch + ragged tail; here: order[] is in
//    LDS so next pass's chars int4 loads still issue before the current
//    gather (r6 pipeline kept), and DESCENDING order puts the 44-bag ragged
//    tail pass on the cheapest (len 1-2) bags.
//  - Gather body identical to r6 (13 lanes/bag, ds_read_b128, 56-dword rows).
//  - Known cost: stores scatter at 200B granularity in a 100KB window
//    (~+8MB WRITE from shared-line RMW, r5 evidence). DS saving should win.

constexpr int EMB     = 50;
constexpr int RSTRIDE = 56;                  // dwords per padded row
constexpr int TBL_F   = 256 * RSTRIDE;       // 14336 floats = 57344 B
constexpr int NBAGS   = 1024 * 256;          // 262144
constexpr int BLOCK   = 1024;
constexpr int TPB     = 13;                  // lanes per bag
constexpr int BPP     = BLOCK / TPB;         // 78 bags per pass
constexpr int CHUNK   = 512;                 // bags per block
constexpr int NPASS   = (CHUNK + BPP - 1) / BPP;  // 7 (tail pass: 44 bags)
constexpr int BLOCKS  = NBAGS / CHUNK;       // 512, exact

__global__ __launch_bounds__(BLOCK, 8) void embag_sortpipe_kernel(
    const int*   __restrict__ chars,     // [NBAGS, W=16]
    const int*   __restrict__ lengths,   // [NBAGS]
    const float* __restrict__ table,     // [256, EMB]
    float*       __restrict__ out)       // [NBAGS, EMB]
{
    __shared__ float          tbl[TBL_F];
    __shared__ unsigned short order[CHUNK];   // (len<<9) | local_bag_id
    __shared__ unsigned       bins[17];
    __shared__ float          invl[17];

    const int base = blockIdx.x * CHUNK;

    if (threadIdx.x < 17) {
        bins[threadIdx.x] = 0;
        invl[threadIdx.x] = threadIdx.x ? 1.0f / (float)threadIdx.x : 0.0f;
    }
    // Stage table into padded fp32 layout (cols 50..55 zero).
    for (int i = threadIdx.x; i < TBL_F; i += BLOCK) {
        const int r = i / RSTRIDE;
        const int c = i - r * RSTRIDE;
        tbl[i] = (c < EMB) ? table[r * EMB + c] : 0.0f;
    }
    // Histogram this block's 512 lengths (bins zeroed by lane order within
    // the first wave before any atomic from it; other waves ordered by the
    // barrier below? No -- need bins ready before atomics: use syncthreads.)
    __syncthreads();

    int myLen = 0, myTicket = 0;
    if (threadIdx.x < CHUNK) {
        myLen = lengths[base + threadIdx.x];              // in [1,16]
        myTicket = (int)atomicAdd(&bins[myLen], 1u);
    }
    __syncthreads();
    if (threadIdx.x == 0) {       // descending start offsets: len=16 first
        unsigned s = 0;
        for (int l = 16; l >= 1; --l) { unsigned c = bins[l]; bins[l] = s; s += c; }
    }
    __syncthreads();
    if (threadIdx.x < CHUNK)
        order[bins[myLen] + myTicket] =
            (unsigned short)((myLen << 9) | threadIdx.x);
    __syncthreads();

    const int  lb     = threadIdx.x / TPB;             // bag slot in pass
    const int  t      = threadIdx.x - lb * TPB;        // 16B slot in row
    const bool active = (lb < BPP);
    const float* rowp = tbl + 4 * t;

    // Prologue: read slot-0 order + prefetch its chars.
    int oi = active ? lb : 0;
    unsigned ord = order[oi];
    {
        const int4* cp = reinterpret_cast<const int4*>(
            chars + (size_t)(base + (int)(ord & 511u)) * 16);
        // fallthrough into loop with c0..c3 live
    }
    const int4* cp0 = reinterpret_cast<const int4*>(
        chars + (size_t)(base + (int)(ord & 511u)) * 16);
    int4 c0 = cp0[0], c1 = cp0[1], c2 = cp0[2], c3 = cp0[3];

    for (int p = 0; p < NPASS; ++p) {
        // Prefetch next pass: order[] is already in LDS, so the chars loads
        // issue immediately and retire under the gathers below.
        const int oin = (oi + BPP < CHUNK) ? oi + BPP : CHUNK - 1;
        const unsigned ordn = order[oin];
        const int4* cpn = reinterpret_cast<const int4*>(
            chars + (size_t)(base + (int)(ordn & 511u)) * 16);
        const int4 n0 = cpn[0], n1 = cpn[1], n2 = cpn[2], n3 = cpn[3];

        if (active && oi < CHUNK) {
            const int len = (int)(ord >> 9);
            const int bag = base + (int)(ord & 511u);

            float4 acc = make_float4(0.f, 0.f, 0.f, 0.f);

            #define G(comp)                                                        \
                {                                                                  \
                    const float4 v =                                               \
                        *reinterpret_cast<const float4*>(rowp + (comp) * RSTRIDE); \
                    acc.x += v.x; acc.y += v.y; acc.z += v.z; acc.w += v.w;        \
                }
            G(c0.x)
            if (len > 1)  { G(c0.y)
            if (len > 2)  { G(c0.z)
            if (len > 3)  { G(c0.w)
            if (len > 4)  { G(c1.x)
            if (len > 5)  { G(c1.y)
            if (len > 6)  { G(c1.z)
            if (len > 7)  { G(c1.w)
            if (len > 8)  { G(c2.x)
            if (len > 9)  { G(c2.y)
            if (len > 10) { G(c2.z)
            if (len > 11) { G(c2.w)
            if (len > 12) { G(c3.x)
            if (len > 13) { G(c3.y)
            if (len > 14) { G(c3.z)
            if (len > 15) { G(c3.w) }}}}}}}}}}}}}}}
            #undef G

            const float inv = invl[len];
            float* ob = out + (size_t)bag * EMB + 4u * (unsigned)t;
            reinterpret_cast<float2*>(ob)[0] = make_float2(acc.x * inv, acc.y * inv);
            if (t < 12)
                reinterpret_cast<float2*>(ob)[1] = make_float2(acc.z * inv, acc.w * inv);
        }

        ord = ordn;
        c0 = n0; c1 = n1; c2 = n2; c3 = n3;
        oi += BPP;
    }
}

extern "C" void kernel_launch(void* const* d_in, const int* in_sizes, int n_in,
                              void* d_out, int out_size, void* d_ws, size_t ws_size,
                              hipStream_t stream) {
    const int*   chars   = (const int*)d_in[0];   // [B,S,W] int32
    const int*   lengths = (const int*)d_in[1];   // [B,S]   int32
    const float* table   = (const float*)d_in[2]; // [256,50] f32
    float*       out     = (float*)d_out;         // [B,S,50] f32

    embag_sortpipe_kernel<<<dim3(BLOCKS), dim3(BLOCK), 0, stream>>>(
        chars, lengths, table, out);
}